// Round 11
// baseline (46.391 us; speedup 1.0000x reference)
//
#include <hip/hip_runtime.h>

// out[b,s,h,w] = sum_t input[b,s,t,h,w] * weight[t, h%8, w%8]   (h,w < 256; else 0)
// output[b, s*1024 + i*32 + j, q*16 + p] = out[b,s, 8i+p, 8j+q]   i,j in [0,32), p,q in [0,16)
//
// Round-11: barrier-free register scatter. No LDS tile, no phase 2, no data
// barriers. Thread owns a 4-row x 1-col strip (rows quad-aligned): 64 dword
// loads (wave = 256B contiguous bursts; sched_barrier fence keeps 16KB/wave
// in flight - R10's verified win), FMA, then each of the <=4 window
// memberships (2 row-classes x 2 col-classes) is ONE aligned dwordx4 store
// (p-contiguous in k; 16B grains merge losslessly per R9 WRITE_SIZE evidence).
// Stores flow inside the load stream -> mixed read/write traffic chip-wide.
//
// Membership algebra for pixel (h,w), h=8*i1+p1 (p1<8), i2=i1-1 (p=p1+8);
// w=8*jA+qA (qA<8), jB=jA-1 (q=qA+8). Padding: window-row 31 p>=8 (rows
// 256..263) and window-col 31 q>=8 (cols 256..263) zero-filled with disjoint
// per-block ownership.

namespace {

constexpr int TT = 16;

__global__ __launch_bounds__(512, 4) void meas_kernel(
    const float* __restrict__ in, const float* __restrict__ wt,
    float* __restrict__ out)
{
    __shared__ float wlds[TT * 64];

    const int tid = threadIdx.x;
    for (int idx = tid; idx < TT * 64; idx += 512) wlds[idx] = wt[idx];

    // XCD swizzle: 512 blocks, 8 XCDs -> 64 logical blocks (one b) per XCD;
    // g-neighbors (who share output cache lines) adjacent -> co-XCD, co-time.
    const int bid = (blockIdx.x & 7) * 64 + (blockIdx.x >> 3);
    const int g = bid & 15;
    const int s = (bid >> 4) & 3;
    const int b = bid >> 6;

    const float* __restrict__ inp = in + (size_t)(b * 4 + s) * TT * 65536;
    float* __restrict__ outb = out + ((size_t)b * 4096 + (size_t)s * 1024) * 256;

    // ---- padding zero-fills (disjoint from all data stores; no sync needed) ----
    const float4 z4 = make_float4(0.f, 0.f, 0.f, 0.f);
    // col-padding (j=31, q>=8) owned by the block owning the source rows:
    //   class X: i=2g   (p0 in {0,4,8,12})  class Y: i=2g-1 (p0 in {8,12})
    //   class Z: i=2g+1 (p0 in {0,4})
    if (tid < 64) {
        int i, q, p0;
        if (tid < 32)      { i = 2*g;     q = 8 + (tid & 7); p0 = (tid >> 3) * 4; }
        else if (tid < 48) { i = 2*g - 1; q = 8 + (tid & 7); p0 = 8 + ((tid >> 3) & 1) * 4; }
        else               { i = 2*g + 1; q = 8 + (tid & 7); p0 = ((tid >> 3) & 1) * 4; }
        if (i >= 0)
            *reinterpret_cast<float4*>(outb + (size_t)(i * 32 + 31) * 256 + q * 16 + p0) = z4;
    }
    // row-padding (i=31, p>=8) <- image rows 256..263: all j, all q (g==15 owns)
    if (g == 15) {
        for (int u = tid; u < 1024; u += 512) {
            const int j = u >> 5, e = u & 31, q = e >> 1, p0 = 8 + (e & 1) * 4;
            *reinterpret_cast<float4*>(outb + (size_t)(992 + j) * 256 + q * 16 + p0) = z4;
        }
    }

    __syncthreads();   // weights visible -- the ONLY barrier

    // ---- main stream: 1024 strips of (4 rows x 1 col), 2 per thread ----
#pragma unroll 1
    for (int m = 0; m < 2; ++m) {
        const int slot = m * 512 + tid;
        const int rq  = slot >> 8;          // row-quad 0..3 (wave-uniform)
        const int col = slot & 255;         // image col (lanes consecutive)
        const int h0  = g * 16 + rq * 4;    // quad-aligned -> h0&7 in {0,4}

        // 1) issue all 64 loads (16KB/wave in flight)
        float v[4][TT];
#pragma unroll
        for (int rr = 0; rr < 4; ++rr) {
            const float* gp = inp + (h0 + rr) * 256 + col;
#pragma unroll
            for (int t = 0; t < TT; ++t)
                v[rr][t] = gp[t * 65536];
        }

        __builtin_amdgcn_sched_barrier(0);   // no FMA hoisted above this

        // 2) FMA (weights: 8 distinct LDS addrs/wave, bank-consecutive broadcast)
        float acc[4] = {0.f, 0.f, 0.f, 0.f};
#pragma unroll
        for (int rr = 0; rr < 4; ++rr) {
            const float* wr = &wlds[((h0 + rr) & 7) * 8 + (col & 7)];
#pragma unroll
            for (int t = 0; t < TT; ++t)
                acc[rr] += v[rr][t] * wr[t * 64];
        }

        // 3) scatter: <=4 dwordx4 stores (p-quad contiguous in k)
        const int i1 = h0 >> 3, p1 = h0 & 7;   // p1 in {0,4}
        const int i2 = i1 - 1;                 // p = p1+8
        const int jA = col >> 3, qA = col & 7;
        const int jB = jA - 1,   qB = qA + 8;
        const float4 a4 = make_float4(acc[0], acc[1], acc[2], acc[3]);

        *reinterpret_cast<float4*>(outb + (size_t)(i1 * 32 + jA) * 256 + qA * 16 + p1) = a4;
        if (jB >= 0)
            *reinterpret_cast<float4*>(outb + (size_t)(i1 * 32 + jB) * 256 + qB * 16 + p1) = a4;
        if (i2 >= 0) {   // wave-uniform (h0 wave-uniform)
            *reinterpret_cast<float4*>(outb + (size_t)(i2 * 32 + jA) * 256 + qA * 16 + p1 + 8) = a4;
            if (jB >= 0)
                *reinterpret_cast<float4*>(outb + (size_t)(i2 * 32 + jB) * 256 + qB * 16 + p1 + 8) = a4;
        }
    }
}

} // namespace

extern "C" void kernel_launch(void* const* d_in, const int* in_sizes, int n_in,
                              void* d_out, int out_size, void* d_ws, size_t ws_size,
                              hipStream_t stream) {
    const float* in = (const float*)d_in[0];
    const float* wt = (const float*)d_in[1];
    float* out      = (float*)d_out;
    hipLaunchKernelGGL(meas_kernel, dim3(512), dim3(512), 0, stream, in, wt, out);
}

// Round 12
// 31.786 us; speedup vs baseline: 1.4595x; 1.4595x over previous
//
#include <hip/hip_runtime.h>

// out[b,s,h,w] = sum_t input[b,s,t,h,w] * weight[t, h%8, w%8]   (h,w < 256; else 0)
// output[b, s*1024 + i*32 + j, q*16 + p] = out[b,s, 8i+p, 8j+q]   i,j in [0,32), p,q in [0,16)
//
// Round-12: R10's proven 2-phase LDS structure at finer granularity for phase
// desync: 1024 blocks x 256 threads = 4 blocks/CU. Block (b,s,g), g in 0..31,
// owns image rows [8g, 8g+8) disjointly (zero halo). Per-thread load schedule
// identical to R10 (2 m-iters x 16-float4 batch + sched_barrier fence).
// Phase 2: each pixel's two window memberships are half-window stores:
//   (i=g,   p = h&7      < 8)  and  (i=g-1, p = (h&7)+8),
// 16B p-contiguous grains, temporally clustered per block (merge per R9).
// Col padding via zeroed LDS halo cols; row padding (i=31, p>=8) by g==31.

namespace {

constexpr int TT   = 16;
constexpr int LDSW = 268;   // 264 cols + 4 pad

__global__ __launch_bounds__(256, 4) void meas_kernel(
    const float* __restrict__ in, const float* __restrict__ wt,
    float* __restrict__ out)
{
    __shared__ float tile[8 * LDSW];
    __shared__ float wlds[TT * 64];

    const int tid = threadIdx.x;
    for (int idx = tid; idx < TT * 64; idx += 256) wlds[idx] = wt[idx];

    // zero halo cols 256..263 (c4 slots 64,65) of the 8 tile rows
    if (tid < 16) {
        const int r  = tid >> 1;
        const int c4 = 64 + (tid & 1);
        *reinterpret_cast<float4*>(&tile[r * LDSW + c4 * 4]) =
            make_float4(0.f, 0.f, 0.f, 0.f);
    }

    // XCD swizzle: 1024 blocks, 8 XCDs -> 128 logical blocks (one b) per XCD;
    // g-neighbors (output line partners) adjacent -> co-XCD, co-time.
    const int bid = (blockIdx.x & 7) * 128 + (blockIdx.x >> 3);
    const int g = bid & 31;
    const int s = (bid >> 5) & 3;
    const int b = bid >> 7;

    const float* __restrict__ inp = in + (size_t)(b * 4 + s) * TT * 65536;
    float* __restrict__ outb = out + ((size_t)b * 4096 + (size_t)s * 1024) * 256;

    __syncthreads();   // weights + halo zeros visible

    // ---- Phase 1: t-sum of rows [8g, 8g+8) into LDS ----
    // slot = m*256 + tid: r = slot>>6 (wave-uniform), lane c -> w = 4c.
    // Per t: one aligned contiguous 1KB wave burst. No bounds checks.
#pragma unroll 1
    for (int m = 0; m < 2; ++m) {
        const int slot = m * 256 + tid;
        const int r = slot >> 6;      // 0..7
        const int c = slot & 63;
        const int h = g * 8 + r;
        const int w = c * 4;
        const float* gp = inp + h * 256 + w;

        // 1) issue all 16 strided 1KB bursts back-to-back (16KB/wave in flight)
        float4 v[TT];
#pragma unroll
        for (int t = 0; t < TT; ++t)
            v[t] = *reinterpret_cast<const float4*>(gp + t * 65536);

        __builtin_amdgcn_sched_barrier(0);   // no FMA hoisted above

        // 2) FMA against LDS-resident weights
        const float* wrow = &wlds[(h & 7) * 8 + (w & 7)];
        float4 acc = make_float4(0.f, 0.f, 0.f, 0.f);
#pragma unroll
        for (int t = 0; t < TT; ++t) {
            const float4 wv = *reinterpret_cast<const float4*>(wrow + t * 64);
            acc.x += v[t].x * wv.x;
            acc.y += v[t].y * wv.y;
            acc.z += v[t].z * wv.z;
            acc.w += v[t].w * wv.w;
        }
        *reinterpret_cast<float4*>(&tile[r * LDSW + w]) = acc;
    }

    __syncthreads();

    // ---- Phase 2: half-window stores ----
    // f4 unit f in 0..1023 per half: j = f>>5, e = f&31, q = e>>1, pp = (e&1)*4.
    // local tile row = p&7 = pp..pp+3 ; col = 8j+q (<=263, halo zeros for j=31,q>=8).
#pragma unroll
    for (int m2 = 0; m2 < 4; ++m2) {
        const int f  = m2 * 256 + tid;
        const int j  = f >> 5;
        const int e  = f & 31;
        const int q2 = e >> 1;
        const int pp = (e & 1) * 4;
        const float* src = &tile[pp * LDSW + j * 8 + q2];
        const float4 a4 = make_float4(src[0], src[LDSW], src[2 * LDSW], src[3 * LDSW]);

        // membership 1: window-row i = g, p = pp..pp+3 (< 8)
        {
            const int n = 32 * g + j;
            *reinterpret_cast<float4*>(outb + (size_t)n * 256 + q2 * 16 + pp) = a4;
        }
        // membership 2: window-row i = g-1, p = 8+pp..
        if (g > 0) {
            const int n = 32 * (g - 1) + j;
            *reinterpret_cast<float4*>(outb + (size_t)n * 256 + q2 * 16 + 8 + pp) = a4;
        }
        // g==31: padding half (i=31, p>=8) <- image rows 256.. = zeros
        if (g == 31) {
            const int n = 992 + j;
            *reinterpret_cast<float4*>(outb + (size_t)n * 256 + q2 * 16 + 8 + pp) =
                make_float4(0.f, 0.f, 0.f, 0.f);
        }
    }
}

} // namespace

extern "C" void kernel_launch(void* const* d_in, const int* in_sizes, int n_in,
                              void* d_out, int out_size, void* d_ws, size_t ws_size,
                              hipStream_t stream) {
    const float* in = (const float*)d_in[0];
    const float* wt = (const float*)d_in[1];
    float* out      = (float*)d_out;
    hipLaunchKernelGGL(meas_kernel, dim3(1024), dim3(256), 0, stream, in, wt, out);
}